// Round 1
// baseline (388.645 us; speedup 1.0000x reference)
//
#include <hip/hip_runtime.h>
#include <hip/hip_bf16.h>
#include <hip/hip_fp16.h>

// DeepSetPred: encoder MLP (MFMA fp16) -> segment sum -> predictor MLP (fp32)
// T=131072, E=256, H=512, C=256, O=32, NSEG=128

typedef _Float16 half8v __attribute__((ext_vector_type(8)));
typedef _Float16 half4v __attribute__((ext_vector_type(4)));
typedef float f32x4 __attribute__((ext_vector_type(4)));

__device__ __forceinline__ float tanh_fast(float x) {
    // tanh(x) = 1 - 2/(exp(2x)+1); exact identity, hw exp. Handles +-inf fine.
    float e = __expf(2.0f * x);
    return 1.0f - 2.0f / (e + 1.0f);
}

// ---------------- weight transpose + fp16 cast (runs every launch, ~0.5M elems) ----
__global__ void wt_kernel(const float* __restrict__ W1, const float* __restrict__ W2,
                          const float* __restrict__ W3,
                          _Float16* __restrict__ W1T, _Float16* __restrict__ W2T,
                          _Float16* __restrict__ W3T) {
    int idx = blockIdx.x * 256 + threadIdx.x;
    if (idx < 131072) {                       // W1 [256][512] -> W1T [512][256]
        int n = idx >> 8, k = idx & 255;
        W1T[idx] = (_Float16)W1[k * 512 + n];
    } else if (idx < 393216) {                // W2 [512][512] -> W2T [512][512]
        int j = idx - 131072, n = j >> 9, k = j & 511;
        W2T[j] = (_Float16)W2[k * 512 + n];
    } else if (idx < 524288) {                // W3 [512][256] -> W3T [256][512]
        int j = idx - 393216, n = j >> 9, k = j & 511;
        W3T[j] = (_Float16)W3[k * 256 + n];
    }
}

// ---------------- encoder ----------------
// Transposed formulation: D[M=out_feat][N=64 tokens] = WT(MxK) * actT(Kx64).
// A frag: lane reads WT[n=mbase+mt*16+(l&15)][k0..k0+7] (global, 16B).
// B frag: lane reads act[t=nt*16+(l&15)][k0..k0+7] from LDS (16B, XOR-swizzled).
// D frag: lane holds col t=(l&15)+16*nt, rows f=(l>>4)*4+reg -> 4 consecutive
//         features of one token => ds_write_b64 into token-major [t][f] layout.
template<int K, int MT>
__device__ __forceinline__ void mlp_layer(const _Float16* __restrict__ WT, int mbase,
                                          const char* lds_in, int lane,
                                          f32x4 acc[MT][4]) {
    const int kgrp = 8 * (lane >> 4);
    const int r = lane & 15;
    #pragma unroll
    for (int kk = 0; kk < K / 32; ++kk) {
        const int k0 = kk * 32 + kgrp;
        half8v b[4];
        #pragma unroll
        for (int nt = 0; nt < 4; ++nt) {
            int t = nt * 16 + r;
            int off = t * (K * 2) + ((k0 * 2) ^ ((t & 7) << 4));
            b[nt] = *(const half8v*)(lds_in + off);
        }
        half8v a[MT];
        #pragma unroll
        for (int mt = 0; mt < MT; ++mt) {
            int n = mbase + mt * 16 + r;
            a[mt] = *(const half8v*)(WT + (size_t)n * K + k0);
        }
        #pragma unroll
        for (int mt = 0; mt < MT; ++mt)
            #pragma unroll
            for (int nt = 0; nt < 4; ++nt)
                acc[mt][nt] = __builtin_amdgcn_mfma_f32_16x16x32_f16(
                    a[mt], b[nt], acc[mt][nt], 0, 0, 0);
    }
}

__device__ __forceinline__ void store_h(char* lds_out, const f32x4 acc[4][4],
                                        const float* sbias, int mbase, int lane) {
    const int r = lane & 15;
    const int fr0 = (lane >> 4) * 4;
    #pragma unroll
    for (int mt = 0; mt < 4; ++mt) {
        int f0 = mbase + mt * 16 + fr0;
        #pragma unroll
        for (int nt = 0; nt < 4; ++nt) {
            int t = nt * 16 + r;
            half4v hv;
            #pragma unroll
            for (int reg = 0; reg < 4; ++reg) {
                float v = acc[mt][nt][reg] + sbias[f0 + reg];
                hv[reg] = (_Float16)tanh_fast(v);
            }
            int off = t * 1024 + ((f0 * 2) ^ ((t & 7) << 4));  // row stride 512 fp16
            *(half4v*)(lds_out + off) = hv;
        }
    }
}

__global__ __launch_bounds__(512, 2) void encoder_kernel(
    const float* __restrict__ words, const int* __restrict__ seg_ids,
    const _Float16* __restrict__ W1T, const _Float16* __restrict__ W2T,
    const _Float16* __restrict__ W3T,
    const float* __restrict__ b1, const float* __restrict__ b2,
    const float* __restrict__ b3, float* __restrict__ enc) {
    __shared__ char buf0[65536];   // words [64][256] fp16 (32KB) then h2 [64][512]
    __shared__ char buf1[65536];   // h1 [64][512] fp16, then encT [256][64] f32
    __shared__ float sbias[1280];  // b1(512) b2(512) b3(256)
    __shared__ int sseg[64];

    const int tid = threadIdx.x;
    const int lane = tid & 63;
    const int wave = tid >> 6;
    const int tok0 = blockIdx.x * 64;

    sbias[tid] = b1[tid];
    sbias[512 + tid] = b2[tid];
    if (tid < 256) sbias[1024 + tid] = b3[tid];
    if (tid < 64) sseg[tid] = seg_ids[tok0 + tid];

    // stage words tile -> fp16 LDS, token-major [t][k], XOR-swizzled, coalesced fp32 reads
    const float* wsrc = words + (size_t)tok0 * 256;
    #pragma unroll
    for (int it = 0; it < 8; ++it) {
        int i = it * 512 + tid;            // float4 index, 4096 total
        float4 v = ((const float4*)wsrc)[i];
        int t = i >> 6;                    // 64 float4 per 256-float row
        int k = (i & 63) * 4;
        half4v hv = { (_Float16)v.x, (_Float16)v.y, (_Float16)v.z, (_Float16)v.w };
        int off = t * 512 + ((k * 2) ^ ((t & 7) << 4));
        *(half4v*)(buf0 + off) = hv;
    }
    __syncthreads();

    // layer 1: [64][256] -> [64][512]
    {
        f32x4 acc[4][4] = {};
        mlp_layer<256, 4>(W1T, wave * 64, buf0, lane, acc);
        store_h(buf1, acc, sbias, wave * 64, lane);
    }
    __syncthreads();

    // layer 2: [64][512] -> [64][512]
    {
        f32x4 acc[4][4] = {};
        mlp_layer<512, 4>(W2T, wave * 64, buf1, lane, acc);
        store_h(buf0, acc, sbias + 512, wave * 64, lane);
    }
    __syncthreads();

    // layer 3: [64][512] -> [64][256], fp32 out (+bias, no tanh) into encT
    {
        f32x4 acc[2][4] = {};
        mlp_layer<512, 2>(W3T, wave * 32, buf0, lane, acc);
        float* encT = (float*)buf1;        // [f][t^(f&31)] conflict-free column reads
        const int r = lane & 15;
        const int fr0 = (lane >> 4) * 4;
        #pragma unroll
        for (int mt = 0; mt < 2; ++mt) {
            int f0 = wave * 32 + mt * 16 + fr0;
            #pragma unroll
            for (int nt = 0; nt < 4; ++nt) {
                int t = nt * 16 + r;
                #pragma unroll
                for (int reg = 0; reg < 4; ++reg) {
                    int f = f0 + reg;
                    encT[f * 64 + (t ^ (f & 31))] = acc[mt][nt][reg] + sbias[1024 + f];
                }
            }
        }
    }
    __syncthreads();

    // segment reduction: seg_ids sorted -> running sum per feature, atomic on boundary.
    // thread = (feature, half): 512 threads, 32 tokens each, uniform branch per wave.
    {
        int f = tid & 255;
        int hh = tid >> 8;
        int t0 = hh * 32;
        const float* encT = (const float*)buf1;
        float a = 0.0f;
        int cur = sseg[t0];
        for (int i = 0; i < 32; ++i) {
            int t = t0 + i;
            float v = encT[f * 64 + (t ^ (f & 31))];
            int s = sseg[t];
            if (s != cur) { atomicAdd(&enc[cur * 256 + f], a); a = 0.0f; cur = s; }
            a += v;
        }
        atomicAdd(&enc[cur * 256 + f], a);
    }
}

// ---------------- predictor (tiny, fp32) ----------------
__global__ __launch_bounds__(256) void pred_kernel(
    const float* __restrict__ enc,
    const float* __restrict__ P1, const float* __restrict__ pb1,
    const float* __restrict__ P2, const float* __restrict__ pb2,
    const float* __restrict__ P3, const float* __restrict__ pb3,
    float* __restrict__ out) {
    __shared__ float se[256];
    __shared__ float sp[512];
    __shared__ float red[256];
    const int tid = threadIdx.x, b = blockIdx.x;
    se[tid] = enc[b * 256 + tid];
    __syncthreads();
    float a0 = pb1[tid], a1 = pb1[tid + 256];
    for (int k = 0; k < 256; ++k) {
        float e = se[k];
        a0 = fmaf(e, P1[k * 512 + tid], a0);
        a1 = fmaf(e, P1[k * 512 + tid + 256], a1);
    }
    sp[tid] = tanhf(a0);
    sp[tid + 256] = tanhf(a1);
    __syncthreads();
    a0 = pb2[tid]; a1 = pb2[tid + 256];
    for (int k = 0; k < 512; ++k) {
        float p = sp[k];
        a0 = fmaf(p, P2[k * 512 + tid], a0);
        a1 = fmaf(p, P2[k * 512 + tid + 256], a1);
    }
    __syncthreads();
    sp[tid] = tanhf(a0);
    sp[tid + 256] = tanhf(a1);
    __syncthreads();
    int j = tid & 31, part = tid >> 5;
    float s = 0.0f;
    for (int k = part * 64; k < part * 64 + 64; ++k)
        s = fmaf(sp[k], P3[k * 32 + j], s);
    red[tid] = s;
    __syncthreads();
    if (tid < 128) red[tid] += red[tid + 128];
    __syncthreads();
    if (tid < 64) red[tid] += red[tid + 64];
    __syncthreads();
    if (tid < 32) out[b * 32 + tid] = red[tid] + red[tid + 32] + pb3[tid];
}

extern "C" void kernel_launch(void* const* d_in, const int* in_sizes, int n_in,
                              void* d_out, int out_size, void* d_ws, size_t ws_size,
                              hipStream_t stream) {
    const float* words = (const float*)d_in[0];
    const int* seg_ids = (const int*)d_in[1];
    const float* W1 = (const float*)d_in[2];
    const float* b1 = (const float*)d_in[3];
    const float* W2 = (const float*)d_in[4];
    const float* b2 = (const float*)d_in[5];
    const float* W3 = (const float*)d_in[6];
    const float* b3 = (const float*)d_in[7];
    const float* P1 = (const float*)d_in[8];
    const float* pb1 = (const float*)d_in[9];
    const float* P2 = (const float*)d_in[10];
    const float* pb2 = (const float*)d_in[11];
    const float* P3 = (const float*)d_in[12];
    const float* pb3 = (const float*)d_in[13];
    float* out = (float*)d_out;

    char* ws = (char*)d_ws;
    _Float16* W1T = (_Float16*)(ws);            // 512*256*2 = 256KB
    _Float16* W2T = (_Float16*)(ws + 262144);   // 512*512*2 = 512KB
    _Float16* W3T = (_Float16*)(ws + 786432);   // 256*512*2 = 256KB
    float* enc = (float*)(ws + 1048576);        // 128*256*4 = 128KB

    hipMemsetAsync(enc, 0, 128 * 256 * 4, stream);
    wt_kernel<<<524288 / 256, 256, 0, stream>>>(W1, W2, W3, W1T, W2T, W3T);
    encoder_kernel<<<2048, 512, 0, stream>>>(words, seg_ids, W1T, W2T, W3T,
                                             b1, b2, b3, enc);
    pred_kernel<<<128, 256, 0, stream>>>(enc, P1, pb1, P2, pb2, P3, pb3, out);
}

// Round 2
// 322.592 us; speedup vs baseline: 1.2048x; 1.2048x over previous
//
#include <hip/hip_runtime.h>
#include <hip/hip_bf16.h>
#include <hip/hip_fp16.h>

// DeepSetPred: encoder MLP (MFMA fp16) -> segment sum -> predictor MLP (fp32)
// T=131072, E=256, H=512, C=256, O=32, NSEG=128
// R1: single 64KB LDS buffer reused across layers (words->h1->h2->encT in place)
//     => 69.3KB/block => 2 blocks/CU (was 133.5KB, 1 block/CU).
//     Swizzle widened to (t&15)<<4 for 2-way-free store_h writes.

typedef _Float16 half8v __attribute__((ext_vector_type(8)));
typedef _Float16 half4v __attribute__((ext_vector_type(4)));
typedef float f32x4 __attribute__((ext_vector_type(4)));

__device__ __forceinline__ float tanh_fast(float x) {
    float e = __expf(2.0f * x);
    return 1.0f - 2.0f / (e + 1.0f);
}

// ---------------- weight transpose + fp16 cast ----------------
__global__ void wt_kernel(const float* __restrict__ W1, const float* __restrict__ W2,
                          const float* __restrict__ W3,
                          _Float16* __restrict__ W1T, _Float16* __restrict__ W2T,
                          _Float16* __restrict__ W3T) {
    int idx = blockIdx.x * 256 + threadIdx.x;
    if (idx < 131072) {                       // W1 [256][512] -> W1T [512][256]
        int n = idx >> 8, k = idx & 255;
        W1T[idx] = (_Float16)W1[k * 512 + n];
    } else if (idx < 393216) {                // W2 [512][512] -> W2T [512][512]
        int j = idx - 131072, n = j >> 9, k = j & 511;
        W2T[j] = (_Float16)W2[k * 512 + n];
    } else if (idx < 524288) {                // W3 [512][256] -> W3T [256][512]
        int j = idx - 393216, n = j >> 9, k = j & 511;
        W3T[j] = (_Float16)W3[k * 256 + n];
    }
}

// ---------------- encoder ----------------
// Transposed formulation: D[M=out_feat][N=64 tokens] = WT(MxK) * actT(Kx64).
// LDS act layout: token-major [t][k] fp16, byte off = t*K*2 + ((k*2) ^ ((t&15)<<4)).
template<int K, int MT>
__device__ __forceinline__ void mlp_layer(const _Float16* __restrict__ WT, int mbase,
                                          const char* lds_in, int lane,
                                          f32x4 acc[MT][4]) {
    const int kgrp = 8 * (lane >> 4);
    const int r = lane & 15;
    #pragma unroll
    for (int kk = 0; kk < K / 32; ++kk) {
        const int k0 = kk * 32 + kgrp;
        half8v b[4];
        #pragma unroll
        for (int nt = 0; nt < 4; ++nt) {
            int t = nt * 16 + r;
            int off = t * (K * 2) + ((k0 * 2) ^ ((t & 15) << 4));
            b[nt] = *(const half8v*)(lds_in + off);
        }
        half8v a[MT];
        #pragma unroll
        for (int mt = 0; mt < MT; ++mt) {
            int n = mbase + mt * 16 + r;
            a[mt] = *(const half8v*)(WT + (size_t)n * K + k0);
        }
        #pragma unroll
        for (int mt = 0; mt < MT; ++mt)
            #pragma unroll
            for (int nt = 0; nt < 4; ++nt)
                acc[mt][nt] = __builtin_amdgcn_mfma_f32_16x16x32_f16(
                    a[mt], b[nt], acc[mt][nt], 0, 0, 0);
    }
}

// D frag -> tanh -> fp16 LDS [t][f], row stride 512 feats (1024B), swizzled.
__device__ __forceinline__ void store_h(char* lds_out, const f32x4 acc[4][4],
                                        const float* sbias, int mbase, int lane) {
    const int r = lane & 15;
    const int fr0 = (lane >> 4) * 4;
    #pragma unroll
    for (int mt = 0; mt < 4; ++mt) {
        int f0 = mbase + mt * 16 + fr0;
        #pragma unroll
        for (int nt = 0; nt < 4; ++nt) {
            int t = nt * 16 + r;
            half4v hv;
            #pragma unroll
            for (int reg = 0; reg < 4; ++reg) {
                float v = acc[mt][nt][reg] + sbias[f0 + reg];
                hv[reg] = (_Float16)tanh_fast(v);
            }
            int off = t * 1024 + ((f0 * 2) ^ ((t & 15) << 4));
            *(half4v*)(lds_out + off) = hv;
        }
    }
}

__global__ __launch_bounds__(512, 4) void encoder_kernel(
    const float* __restrict__ words, const int* __restrict__ seg_ids,
    const _Float16* __restrict__ W1T, const _Float16* __restrict__ W2T,
    const _Float16* __restrict__ W3T,
    const float* __restrict__ b1, const float* __restrict__ b2,
    const float* __restrict__ b3, float* __restrict__ enc) {
    __shared__ __align__(16) char buf[65536]; // words[64][256]f16 / h[64][512]f16 / encT[256][64]f32
    __shared__ float sbias[1280];             // b1(512) b2(512) b3(256)
    __shared__ int sseg[64];

    const int tid = threadIdx.x;
    const int lane = tid & 63;
    const int wave = tid >> 6;
    const int tok0 = blockIdx.x * 64;

    sbias[tid] = b1[tid];
    sbias[512 + tid] = b2[tid];
    if (tid < 256) sbias[1024 + tid] = b3[tid];
    if (tid < 64) sseg[tid] = seg_ids[tok0 + tid];

    // stage words tile -> fp16 LDS, token-major [t][k] (row 512B), swizzled
    const float* wsrc = words + (size_t)tok0 * 256;
    #pragma unroll
    for (int it = 0; it < 8; ++it) {
        int i = it * 512 + tid;            // float4 index, 4096 total
        float4 v = ((const float4*)wsrc)[i];
        int t = i >> 6;
        int k = (i & 63) * 4;
        half4v hv = { (_Float16)v.x, (_Float16)v.y, (_Float16)v.z, (_Float16)v.w };
        int off = t * 512 + ((k * 2) ^ ((t & 15) << 4));
        *(half4v*)(buf + off) = hv;
    }
    __syncthreads();

    // layer 1: words[64][256] -> h1[64][512] (in place)
    {
        f32x4 acc[4][4] = {};
        mlp_layer<256, 4>(W1T, wave * 64, buf, lane, acc);
        __syncthreads();                   // all reads of words done
        store_h(buf, acc, sbias, wave * 64, lane);
    }
    __syncthreads();

    // layer 2: h1[64][512] -> h2[64][512] (in place)
    {
        f32x4 acc[4][4] = {};
        mlp_layer<512, 4>(W2T, wave * 64, buf, lane, acc);
        __syncthreads();
        store_h(buf, acc, sbias + 512, wave * 64, lane);
    }
    __syncthreads();

    // layer 3: h2[64][512] -> encT[256][64] f32 (in place)
    {
        f32x4 acc[2][4] = {};
        mlp_layer<512, 2>(W3T, wave * 32, buf, lane, acc);
        __syncthreads();
        float* encT = (float*)buf;         // [f][t ^ (f&31)]
        const int r = lane & 15;
        const int fr0 = (lane >> 4) * 4;
        #pragma unroll
        for (int mt = 0; mt < 2; ++mt) {
            int f0 = wave * 32 + mt * 16 + fr0;
            #pragma unroll
            for (int nt = 0; nt < 4; ++nt) {
                int t = nt * 16 + r;
                #pragma unroll
                for (int reg = 0; reg < 4; ++reg) {
                    int f = f0 + reg;
                    encT[f * 64 + (t ^ (f & 31))] = acc[mt][nt][reg] + sbias[1024 + f];
                }
            }
        }
    }
    __syncthreads();

    // segment reduction: sorted seg_ids -> running sum, atomic on boundary
    {
        int f = tid & 255;
        int hh = tid >> 8;
        int t0 = hh * 32;
        const float* encT = (const float*)buf;
        float a = 0.0f;
        int cur = sseg[t0];
        for (int i = 0; i < 32; ++i) {
            int t = t0 + i;
            float v = encT[f * 64 + (t ^ (f & 31))];
            int s = sseg[t];
            if (s != cur) { atomicAdd(&enc[cur * 256 + f], a); a = 0.0f; cur = s; }
            a += v;
        }
        atomicAdd(&enc[cur * 256 + f], a);
    }
}

// ---------------- predictor (tiny, fp32) ----------------
__global__ __launch_bounds__(256) void pred_kernel(
    const float* __restrict__ enc,
    const float* __restrict__ P1, const float* __restrict__ pb1,
    const float* __restrict__ P2, const float* __restrict__ pb2,
    const float* __restrict__ P3, const float* __restrict__ pb3,
    float* __restrict__ out) {
    __shared__ float se[256];
    __shared__ float sp[512];
    __shared__ float red[256];
    const int tid = threadIdx.x, b = blockIdx.x;
    se[tid] = enc[b * 256 + tid];
    __syncthreads();
    float a0 = pb1[tid], a1 = pb1[tid + 256];
    for (int k = 0; k < 256; ++k) {
        float e = se[k];
        a0 = fmaf(e, P1[k * 512 + tid], a0);
        a1 = fmaf(e, P1[k * 512 + tid + 256], a1);
    }
    sp[tid] = tanhf(a0);
    sp[tid + 256] = tanhf(a1);
    __syncthreads();
    a0 = pb2[tid]; a1 = pb2[tid + 256];
    for (int k = 0; k < 512; ++k) {
        float p = sp[k];
        a0 = fmaf(p, P2[k * 512 + tid], a0);
        a1 = fmaf(p, P2[k * 512 + tid + 256], a1);
    }
    __syncthreads();
    sp[tid] = tanhf(a0);
    sp[tid + 256] = tanhf(a1);
    __syncthreads();
    int j = tid & 31, part = tid >> 5;
    float s = 0.0f;
    for (int k = part * 64; k < part * 64 + 64; ++k)
        s = fmaf(sp[k], P3[k * 32 + j], s);
    red[tid] = s;
    __syncthreads();
    if (tid < 128) red[tid] += red[tid + 128];
    __syncthreads();
    if (tid < 64) red[tid] += red[tid + 64];
    __syncthreads();
    if (tid < 32) out[b * 32 + tid] = red[tid] + red[tid + 32] + pb3[tid];
}

extern "C" void kernel_launch(void* const* d_in, const int* in_sizes, int n_in,
                              void* d_out, int out_size, void* d_ws, size_t ws_size,
                              hipStream_t stream) {
    const float* words = (const float*)d_in[0];
    const int* seg_ids = (const int*)d_in[1];
    const float* W1 = (const float*)d_in[2];
    const float* b1 = (const float*)d_in[3];
    const float* W2 = (const float*)d_in[4];
    const float* b2 = (const float*)d_in[5];
    const float* W3 = (const float*)d_in[6];
    const float* b3 = (const float*)d_in[7];
    const float* P1 = (const float*)d_in[8];
    const float* pb1 = (const float*)d_in[9];
    const float* P2 = (const float*)d_in[10];
    const float* pb2 = (const float*)d_in[11];
    const float* P3 = (const float*)d_in[12];
    const float* pb3 = (const float*)d_in[13];
    float* out = (float*)d_out;

    char* ws = (char*)d_ws;
    _Float16* W1T = (_Float16*)(ws);            // 512*256*2 = 256KB
    _Float16* W2T = (_Float16*)(ws + 262144);   // 512*512*2 = 512KB
    _Float16* W3T = (_Float16*)(ws + 786432);   // 256*512*2 = 256KB
    float* enc = (float*)(ws + 1048576);        // 128*256*4 = 128KB

    hipMemsetAsync(enc, 0, 128 * 256 * 4, stream);
    wt_kernel<<<524288 / 256, 256, 0, stream>>>(W1, W2, W3, W1T, W2T, W3T);
    encoder_kernel<<<2048, 512, 0, stream>>>(words, seg_ids, W1T, W2T, W3T,
                                             b1, b2, b3, enc);
    pred_kernel<<<128, 256, 0, stream>>>(enc, P1, pb1, P2, pb2, P3, pb3, out);
}

// Round 3
// 306.370 us; speedup vs baseline: 1.2685x; 1.0530x over previous
//
#include <hip/hip_runtime.h>
#include <hip/hip_bf16.h>
#include <hip/hip_fp16.h>

// DeepSetPred: encoder MLP (MFMA fp16) -> segment sum -> predictor MLP (fp32)
// T=131072, E=256, H=512, C=256, O=32, NSEG=128
// R3: +16B row padding instead of XOR swizzle (bank-balanced AND affine addrs ->
//     one base VGPR + immediate offsets for all ds_read/global_load),
//     bias folded into MFMA C-init, tanh via pre-scaled exp2 (W,b scaled by
//     2*log2e in prep kernel). Goal: arch VGPR <= 64 so (512,4) runs spill-free
//     (R2 spilled: WRITE_SIZE 4.2->89.7MB).

typedef _Float16 half8v __attribute__((ext_vector_type(8)));
typedef _Float16 half4v __attribute__((ext_vector_type(4)));
typedef float f32x4 __attribute__((ext_vector_type(4)));

#define TANH_SCALE 2.8853900817779268f  // 2*log2(e)

// strides (bytes) with +16B pad: conflict-free without XOR, affine in k
#define W_STR 528    // words row: 256 f16 + 8 pad
#define H_STR 1040   // h row: 512 f16 + 8 pad
#define E_STRF 65    // encT row: 64 f32 + 1 pad (floats)

// ---------------- weight transpose + fp16 cast (+tanh prescale) --------------
__global__ void wt_kernel(const float* __restrict__ W1, const float* __restrict__ W2,
                          const float* __restrict__ W3,
                          _Float16* __restrict__ W1T, _Float16* __restrict__ W2T,
                          _Float16* __restrict__ W3T) {
    int idx = blockIdx.x * 256 + threadIdx.x;
    if (idx < 131072) {                       // W1 [256][512] -> W1T [512][256], scaled
        int n = idx >> 8, k = idx & 255;
        W1T[idx] = (_Float16)(W1[k * 512 + n] * TANH_SCALE);
    } else if (idx < 393216) {                // W2 [512][512] -> W2T [512][512], scaled
        int j = idx - 131072, n = j >> 9, k = j & 511;
        W2T[j] = (_Float16)(W2[k * 512 + n] * TANH_SCALE);
    } else if (idx < 524288) {                // W3 [512][256] -> W3T [256][512]
        int j = idx - 393216, n = j >> 9, k = j & 511;
        W3T[j] = (_Float16)W3[k * 256 + n];
    }
}

// ---------------- encoder ----------------
// D[M=out_feat][N=64 tokens] = WT(MxK) * actT(Kx64); acts in LDS [t][k] fp16,
// row stride STR bytes. Bias pre-loaded into the accumulator (uniform over t).
template<int K, int MT, int STR>
__device__ __forceinline__ void mlp_layer(const _Float16* __restrict__ WT, int mbase,
                                          const char* lds_in, const float* sbias_layer,
                                          int lane, f32x4 acc[MT][4]) {
    const int kgrp = 8 * (lane >> 4);
    const int r = lane & 15;
    const int fr0 = (lane >> 4) * 4;
    #pragma unroll
    for (int mt = 0; mt < MT; ++mt) {
        f32x4 bv = *(const f32x4*)(sbias_layer + mbase + mt * 16 + fr0);
        #pragma unroll
        for (int nt = 0; nt < 4; ++nt) acc[mt][nt] = bv;
    }
    const char* bbase = lds_in + r * STR + kgrp * 2;
    const _Float16* abase0 = WT + (size_t)(mbase + r) * K + kgrp;
    #pragma unroll
    for (int kk = 0; kk < K / 32; ++kk) {
        half8v b[4];
        #pragma unroll
        for (int nt = 0; nt < 4; ++nt)
            b[nt] = *(const half8v*)(bbase + nt * 16 * STR + kk * 64);
        half8v a[MT];
        #pragma unroll
        for (int mt = 0; mt < MT; ++mt)
            a[mt] = *(const half8v*)(abase0 + (size_t)mt * 16 * K + kk * 32);
        #pragma unroll
        for (int mt = 0; mt < MT; ++mt)
            #pragma unroll
            for (int nt = 0; nt < 4; ++nt)
                acc[mt][nt] = __builtin_amdgcn_mfma_f32_16x16x32_f16(
                    a[mt], b[nt], acc[mt][nt], 0, 0, 0);
    }
}

// acc (bias included, pre-scaled by 2*log2e) -> tanh -> fp16 LDS [t][f]
__device__ __forceinline__ void store_h(char* lds_out, const f32x4 acc[4][4],
                                        int mbase, int lane) {
    const int r = lane & 15;
    const int fr0 = (lane >> 4) * 4;
    #pragma unroll
    for (int mt = 0; mt < 4; ++mt) {
        int f0 = mbase + mt * 16 + fr0;
        #pragma unroll
        for (int nt = 0; nt < 4; ++nt) {
            int t = nt * 16 + r;
            half4v hv;
            #pragma unroll
            for (int reg = 0; reg < 4; ++reg) {
                float e = __builtin_amdgcn_exp2f(acc[mt][nt][reg]);   // 2^(s*z)
                float rr = __builtin_amdgcn_rcpf(e + 1.0f);
                hv[reg] = (_Float16)fmaf(-2.0f, rr, 1.0f);            // tanh(z)
            }
            *(half4v*)(lds_out + t * H_STR + f0 * 2) = hv;
        }
    }
}

__global__ __launch_bounds__(512, 4) void encoder_kernel(
    const float* __restrict__ words, const int* __restrict__ seg_ids,
    const _Float16* __restrict__ W1T, const _Float16* __restrict__ W2T,
    const _Float16* __restrict__ W3T,
    const float* __restrict__ b1, const float* __restrict__ b2,
    const float* __restrict__ b3, float* __restrict__ enc) {
    __shared__ __align__(16) char buf[66560]; // words 64x528 / h 64x1040 / encT 256x65x4
    __shared__ __align__(16) float sbias[1280]; // s*b1(512) s*b2(512) b3(256)
    __shared__ int sseg[64];

    const int tid = threadIdx.x;
    const int lane = tid & 63;
    const int wave = tid >> 6;
    const int tok0 = blockIdx.x * 64;

    sbias[tid] = b1[tid] * TANH_SCALE;
    sbias[512 + tid] = b2[tid] * TANH_SCALE;
    if (tid < 256) sbias[1024 + tid] = b3[tid];
    if (tid < 64) sseg[tid] = seg_ids[tok0 + tid];

    // stage words tile -> fp16 LDS [t][k], row stride 528B
    const float* wsrc = words + (size_t)tok0 * 256;
    #pragma unroll
    for (int it = 0; it < 8; ++it) {
        int i = it * 512 + tid;            // float4 index, 4096 total
        float4 v = ((const float4*)wsrc)[i];
        int t = i >> 6;
        int col = i & 63;                  // 8B half4 slot within row
        half4v hv = { (_Float16)v.x, (_Float16)v.y, (_Float16)v.z, (_Float16)v.w };
        *(half4v*)(buf + t * W_STR + col * 8) = hv;
    }
    __syncthreads();

    // layer 1: words[64][256] -> h1[64][512] (in place)
    {
        f32x4 acc[4][4];
        mlp_layer<256, 4, W_STR>(W1T, wave * 64, buf, sbias, lane, acc);
        __syncthreads();
        store_h(buf, acc, wave * 64, lane);
    }
    __syncthreads();

    // layer 2: h1 -> h2 (in place)
    {
        f32x4 acc[4][4];
        mlp_layer<512, 4, H_STR>(W2T, wave * 64, buf, sbias + 512, lane, acc);
        __syncthreads();
        store_h(buf, acc, wave * 64, lane);
    }
    __syncthreads();

    // layer 3: h2 -> encT [256][65] f32 (in place; bias pre-loaded, no tanh)
    {
        f32x4 acc[2][4];
        mlp_layer<512, 2, H_STR>(W3T, wave * 32, buf, sbias + 1024, lane, acc);
        __syncthreads();
        float* encT = (float*)buf;
        const int r = lane & 15;
        const int fr0 = (lane >> 4) * 4;
        #pragma unroll
        for (int mt = 0; mt < 2; ++mt) {
            int f0 = wave * 32 + mt * 16 + fr0;
            #pragma unroll
            for (int nt = 0; nt < 4; ++nt) {
                int t = nt * 16 + r;
                #pragma unroll
                for (int reg = 0; reg < 4; ++reg)
                    encT[(f0 + reg) * E_STRF + t] = acc[mt][nt][reg];
            }
        }
    }
    __syncthreads();

    // segment reduction: sorted seg_ids -> running sum, atomic on boundary
    {
        int f = tid & 255;
        int hh = tid >> 8;
        int t0 = hh * 32;
        const float* encT = (const float*)buf;
        float a = 0.0f;
        int cur = sseg[t0];
        for (int i = 0; i < 32; ++i) {
            int t = t0 + i;
            float v = encT[f * E_STRF + t];
            int s = sseg[t];
            if (s != cur) { atomicAdd(&enc[cur * 256 + f], a); a = 0.0f; cur = s; }
            a += v;
        }
        atomicAdd(&enc[cur * 256 + f], a);
    }
}

// ---------------- predictor (tiny, fp32) ----------------
__global__ __launch_bounds__(256) void pred_kernel(
    const float* __restrict__ enc,
    const float* __restrict__ P1, const float* __restrict__ pb1,
    const float* __restrict__ P2, const float* __restrict__ pb2,
    const float* __restrict__ P3, const float* __restrict__ pb3,
    float* __restrict__ out) {
    __shared__ float se[256];
    __shared__ float sp[512];
    __shared__ float red[256];
    const int tid = threadIdx.x, b = blockIdx.x;
    se[tid] = enc[b * 256 + tid];
    __syncthreads();
    float a0 = pb1[tid], a1 = pb1[tid + 256];
    for (int k = 0; k < 256; ++k) {
        float e = se[k];
        a0 = fmaf(e, P1[k * 512 + tid], a0);
        a1 = fmaf(e, P1[k * 512 + tid + 256], a1);
    }
    sp[tid] = tanhf(a0);
    sp[tid + 256] = tanhf(a1);
    __syncthreads();
    a0 = pb2[tid]; a1 = pb2[tid + 256];
    for (int k = 0; k < 512; ++k) {
        float p = sp[k];
        a0 = fmaf(p, P2[k * 512 + tid], a0);
        a1 = fmaf(p, P2[k * 512 + tid + 256], a1);
    }
    __syncthreads();
    sp[tid] = tanhf(a0);
    sp[tid + 256] = tanhf(a1);
    __syncthreads();
    int j = tid & 31, part = tid >> 5;
    float s = 0.0f;
    for (int k = part * 64; k < part * 64 + 64; ++k)
        s = fmaf(sp[k], P3[k * 32 + j], s);
    red[tid] = s;
    __syncthreads();
    if (tid < 128) red[tid] += red[tid + 128];
    __syncthreads();
    if (tid < 64) red[tid] += red[tid + 64];
    __syncthreads();
    if (tid < 32) out[b * 32 + tid] = red[tid] + red[tid + 32] + pb3[tid];
}

extern "C" void kernel_launch(void* const* d_in, const int* in_sizes, int n_in,
                              void* d_out, int out_size, void* d_ws, size_t ws_size,
                              hipStream_t stream) {
    const float* words = (const float*)d_in[0];
    const int* seg_ids = (const int*)d_in[1];
    const float* W1 = (const float*)d_in[2];
    const float* b1 = (const float*)d_in[3];
    const float* W2 = (const float*)d_in[4];
    const float* b2 = (const float*)d_in[5];
    const float* W3 = (const float*)d_in[6];
    const float* b3 = (const float*)d_in[7];
    const float* P1 = (const float*)d_in[8];
    const float* pb1 = (const float*)d_in[9];
    const float* P2 = (const float*)d_in[10];
    const float* pb2 = (const float*)d_in[11];
    const float* P3 = (const float*)d_in[12];
    const float* pb3 = (const float*)d_in[13];
    float* out = (float*)d_out;

    char* ws = (char*)d_ws;
    _Float16* W1T = (_Float16*)(ws);            // 512*256*2 = 256KB
    _Float16* W2T = (_Float16*)(ws + 262144);   // 512*512*2 = 512KB
    _Float16* W3T = (_Float16*)(ws + 786432);   // 256*512*2 = 256KB
    float* enc = (float*)(ws + 1048576);        // 128*256*4 = 128KB

    hipMemsetAsync(enc, 0, 128 * 256 * 4, stream);
    wt_kernel<<<524288 / 256, 256, 0, stream>>>(W1, W2, W3, W1T, W2T, W3T);
    encoder_kernel<<<2048, 512, 0, stream>>>(words, seg_ids, W1T, W2T, W3T,
                                             b1, b2, b3, enc);
    pred_kernel<<<128, 256, 0, stream>>>(enc, P1, pb1, P2, pb2, P3, pb3, out);
}

// Round 4
// 303.118 us; speedup vs baseline: 1.2822x; 1.0107x over previous
//
#include <hip/hip_runtime.h>
#include <hip/hip_bf16.h>
#include <hip/hip_fp16.h>

// DeepSetPred: encoder MLP (MFMA fp16) -> segment sum -> predictor MLP (fp32)
// T=131072, E=256, H=512, C=256, O=32, NSEG=128
// R4: explicit depth-1 A-prefetch software pipeline (kk unrolled x2, disjoint
//     A0/A1 reg sets; A(kk+1) issued before MFMA(kk)). nt-major MFMA order so
//     each ds_read_b128 B-frag hides behind the previous nt's 4 MFMAs.
//     Budget: 64 AGPR acc + ~62 arch VGPR -> spill-free at 4 waves/SIMD.

typedef _Float16 half8v __attribute__((ext_vector_type(8)));
typedef _Float16 half4v __attribute__((ext_vector_type(4)));
typedef float f32x4 __attribute__((ext_vector_type(4)));

#define TANH_SCALE 2.8853900817779268f  // 2*log2(e)

// strides (bytes) with +16B pad: bank-balanced and affine in k
#define W_STR 528    // words row: 256 f16 + 8 pad
#define H_STR 1040   // h row: 512 f16 + 8 pad
#define E_STRF 65    // encT row: 64 f32 + 1 pad (floats)

// ---------------- weight transpose + fp16 cast (+tanh prescale) --------------
__global__ void wt_kernel(const float* __restrict__ W1, const float* __restrict__ W2,
                          const float* __restrict__ W3,
                          _Float16* __restrict__ W1T, _Float16* __restrict__ W2T,
                          _Float16* __restrict__ W3T) {
    int idx = blockIdx.x * 256 + threadIdx.x;
    if (idx < 131072) {                       // W1 [256][512] -> W1T [512][256], scaled
        int n = idx >> 8, k = idx & 255;
        W1T[idx] = (_Float16)(W1[k * 512 + n] * TANH_SCALE);
    } else if (idx < 393216) {                // W2 [512][512] -> W2T [512][512], scaled
        int j = idx - 131072, n = j >> 9, k = j & 511;
        W2T[j] = (_Float16)(W2[k * 512 + n] * TANH_SCALE);
    } else if (idx < 524288) {                // W3 [512][256] -> W3T [256][512]
        int j = idx - 393216, n = j >> 9, k = j & 511;
        W3T[j] = (_Float16)W3[k * 256 + n];
    }
}

// ---------------- encoder ----------------
// D[M=out_feat][N=64 tokens] = WT(MxK) * actT(Kx64); acts in LDS [t][k] fp16.
template<int K, int MT, int STR>
__device__ __forceinline__ void mlp_layer(const _Float16* __restrict__ WT, int mbase,
                                          const char* lds_in, const float* sbias_layer,
                                          int lane, f32x4 acc[MT][4]) {
    const int kgrp = 8 * (lane >> 4);
    const int r = lane & 15;
    const int fr0 = (lane >> 4) * 4;
    #pragma unroll
    for (int mt = 0; mt < MT; ++mt) {
        f32x4 bv = *(const f32x4*)(sbias_layer + mbase + mt * 16 + fr0);
        #pragma unroll
        for (int nt = 0; nt < 4; ++nt) acc[mt][nt] = bv;
    }
    const char* bbase = lds_in + r * STR + kgrp * 2;
    const _Float16* arow = WT + (size_t)(mbase + r) * K + kgrp;

    half8v A0[MT], A1[MT];
    #pragma unroll
    for (int mt = 0; mt < MT; ++mt)
        A0[mt] = *(const half8v*)(arow + (size_t)mt * 16 * K);

    #pragma unroll
    for (int kk = 0; kk < K / 32; kk += 2) {
        // issue prefetch of A(kk+1) before consuming A0(kk)
        #pragma unroll
        for (int mt = 0; mt < MT; ++mt)
            A1[mt] = *(const half8v*)(arow + (size_t)mt * 16 * K + (kk + 1) * 32);
        #pragma unroll
        for (int nt = 0; nt < 4; ++nt) {
            half8v b = *(const half8v*)(bbase + nt * 16 * STR + kk * 64);
            #pragma unroll
            for (int mt = 0; mt < MT; ++mt)
                acc[mt][nt] = __builtin_amdgcn_mfma_f32_16x16x32_f16(
                    A0[mt], b, acc[mt][nt], 0, 0, 0);
        }
        if (kk + 2 < K / 32) {
            #pragma unroll
            for (int mt = 0; mt < MT; ++mt)
                A0[mt] = *(const half8v*)(arow + (size_t)mt * 16 * K + (kk + 2) * 32);
        }
        #pragma unroll
        for (int nt = 0; nt < 4; ++nt) {
            half8v b = *(const half8v*)(bbase + nt * 16 * STR + (kk + 1) * 64);
            #pragma unroll
            for (int mt = 0; mt < MT; ++mt)
                acc[mt][nt] = __builtin_amdgcn_mfma_f32_16x16x32_f16(
                    A1[mt], b, acc[mt][nt], 0, 0, 0);
        }
    }
}

// acc (bias included, pre-scaled by 2*log2e) -> tanh -> fp16 LDS [t][f]
__device__ __forceinline__ void store_h(char* lds_out, const f32x4 acc[4][4],
                                        int mbase, int lane) {
    const int r = lane & 15;
    const int fr0 = (lane >> 4) * 4;
    #pragma unroll
    for (int mt = 0; mt < 4; ++mt) {
        int f0 = mbase + mt * 16 + fr0;
        #pragma unroll
        for (int nt = 0; nt < 4; ++nt) {
            int t = nt * 16 + r;
            half4v hv;
            #pragma unroll
            for (int reg = 0; reg < 4; ++reg) {
                float e = __builtin_amdgcn_exp2f(acc[mt][nt][reg]);   // 2^(s*z)
                float rr = __builtin_amdgcn_rcpf(e + 1.0f);
                hv[reg] = (_Float16)fmaf(-2.0f, rr, 1.0f);            // tanh(z)
            }
            *(half4v*)(lds_out + t * H_STR + f0 * 2) = hv;
        }
    }
}

__global__ __launch_bounds__(512, 4) void encoder_kernel(
    const float* __restrict__ words, const int* __restrict__ seg_ids,
    const _Float16* __restrict__ W1T, const _Float16* __restrict__ W2T,
    const _Float16* __restrict__ W3T,
    const float* __restrict__ b1, const float* __restrict__ b2,
    const float* __restrict__ b3, float* __restrict__ enc) {
    __shared__ __align__(16) char buf[66560]; // words 64x528 / h 64x1040 / encT 256x65x4
    __shared__ __align__(16) float sbias[1280]; // s*b1(512) s*b2(512) b3(256)
    __shared__ int sseg[64];

    const int tid = threadIdx.x;
    const int lane = tid & 63;
    const int wave = tid >> 6;
    const int tok0 = blockIdx.x * 64;

    sbias[tid] = b1[tid] * TANH_SCALE;
    sbias[512 + tid] = b2[tid] * TANH_SCALE;
    if (tid < 256) sbias[1024 + tid] = b3[tid];
    if (tid < 64) sseg[tid] = seg_ids[tok0 + tid];

    // stage words tile -> fp16 LDS [t][k], row stride 528B
    const float* wsrc = words + (size_t)tok0 * 256;
    #pragma unroll
    for (int it = 0; it < 8; ++it) {
        int i = it * 512 + tid;            // float4 index, 4096 total
        float4 v = ((const float4*)wsrc)[i];
        int t = i >> 6;
        int col = i & 63;                  // 8B half4 slot within row
        half4v hv = { (_Float16)v.x, (_Float16)v.y, (_Float16)v.z, (_Float16)v.w };
        *(half4v*)(buf + t * W_STR + col * 8) = hv;
    }
    __syncthreads();

    // layer 1: words[64][256] -> h1[64][512] (in place)
    {
        f32x4 acc[4][4];
        mlp_layer<256, 4, W_STR>(W1T, wave * 64, buf, sbias, lane, acc);
        __syncthreads();
        store_h(buf, acc, wave * 64, lane);
    }
    __syncthreads();

    // layer 2: h1 -> h2 (in place)
    {
        f32x4 acc[4][4];
        mlp_layer<512, 4, H_STR>(W2T, wave * 64, buf, sbias + 512, lane, acc);
        __syncthreads();
        store_h(buf, acc, wave * 64, lane);
    }
    __syncthreads();

    // layer 3: h2 -> encT [256][65] f32 (in place; bias pre-loaded, no tanh)
    {
        f32x4 acc[2][4];
        mlp_layer<512, 2, H_STR>(W3T, wave * 32, buf, sbias + 1024, lane, acc);
        __syncthreads();
        float* encT = (float*)buf;
        const int r = lane & 15;
        const int fr0 = (lane >> 4) * 4;
        #pragma unroll
        for (int mt = 0; mt < 2; ++mt) {
            int f0 = wave * 32 + mt * 16 + fr0;
            #pragma unroll
            for (int nt = 0; nt < 4; ++nt) {
                int t = nt * 16 + r;
                #pragma unroll
                for (int reg = 0; reg < 4; ++reg)
                    encT[(f0 + reg) * E_STRF + t] = acc[mt][nt][reg];
            }
        }
    }
    __syncthreads();

    // segment reduction: sorted seg_ids -> running sum, atomic on boundary
    {
        int f = tid & 255;
        int hh = tid >> 8;
        int t0 = hh * 32;
        const float* encT = (const float*)buf;
        float a = 0.0f;
        int cur = sseg[t0];
        for (int i = 0; i < 32; ++i) {
            int t = t0 + i;
            float v = encT[f * E_STRF + t];
            int s = sseg[t];
            if (s != cur) { atomicAdd(&enc[cur * 256 + f], a); a = 0.0f; cur = s; }
            a += v;
        }
        atomicAdd(&enc[cur * 256 + f], a);
    }
}

// ---------------- predictor (tiny, fp32) ----------------
__global__ __launch_bounds__(256) void pred_kernel(
    const float* __restrict__ enc,
    const float* __restrict__ P1, const float* __restrict__ pb1,
    const float* __restrict__ P2, const float* __restrict__ pb2,
    const float* __restrict__ P3, const float* __restrict__ pb3,
    float* __restrict__ out) {
    __shared__ float se[256];
    __shared__ float sp[512];
    __shared__ float red[256];
    const int tid = threadIdx.x, b = blockIdx.x;
    se[tid] = enc[b * 256 + tid];
    __syncthreads();
    float a0 = pb1[tid], a1 = pb1[tid + 256];
    for (int k = 0; k < 256; ++k) {
        float e = se[k];
        a0 = fmaf(e, P1[k * 512 + tid], a0);
        a1 = fmaf(e, P1[k * 512 + tid + 256], a1);
    }
    sp[tid] = tanhf(a0);
    sp[tid + 256] = tanhf(a1);
    __syncthreads();
    a0 = pb2[tid]; a1 = pb2[tid + 256];
    for (int k = 0; k < 512; ++k) {
        float p = sp[k];
        a0 = fmaf(p, P2[k * 512 + tid], a0);
        a1 = fmaf(p, P2[k * 512 + tid + 256], a1);
    }
    __syncthreads();
    sp[tid] = tanhf(a0);
    sp[tid + 256] = tanhf(a1);
    __syncthreads();
    int j = tid & 31, part = tid >> 5;
    float s = 0.0f;
    for (int k = part * 64; k < part * 64 + 64; ++k)
        s = fmaf(sp[k], P3[k * 32 + j], s);
    red[tid] = s;
    __syncthreads();
    if (tid < 128) red[tid] += red[tid + 128];
    __syncthreads();
    if (tid < 64) red[tid] += red[tid + 64];
    __syncthreads();
    if (tid < 32) out[b * 32 + tid] = red[tid] + red[tid + 32] + pb3[tid];
}

extern "C" void kernel_launch(void* const* d_in, const int* in_sizes, int n_in,
                              void* d_out, int out_size, void* d_ws, size_t ws_size,
                              hipStream_t stream) {
    const float* words = (const float*)d_in[0];
    const int* seg_ids = (const int*)d_in[1];
    const float* W1 = (const float*)d_in[2];
    const float* b1 = (const float*)d_in[3];
    const float* W2 = (const float*)d_in[4];
    const float* b2 = (const float*)d_in[5];
    const float* W3 = (const float*)d_in[6];
    const float* b3 = (const float*)d_in[7];
    const float* P1 = (const float*)d_in[8];
    const float* pb1 = (const float*)d_in[9];
    const float* P2 = (const float*)d_in[10];
    const float* pb2 = (const float*)d_in[11];
    const float* P3 = (const float*)d_in[12];
    const float* pb3 = (const float*)d_in[13];
    float* out = (float*)d_out;

    char* ws = (char*)d_ws;
    _Float16* W1T = (_Float16*)(ws);            // 512*256*2 = 256KB
    _Float16* W2T = (_Float16*)(ws + 262144);   // 512*512*2 = 512KB
    _Float16* W3T = (_Float16*)(ws + 786432);   // 256*512*2 = 256KB
    float* enc = (float*)(ws + 1048576);        // 128*256*4 = 128KB

    hipMemsetAsync(enc, 0, 128 * 256 * 4, stream);
    wt_kernel<<<524288 / 256, 256, 0, stream>>>(W1, W2, W3, W1T, W2T, W3T);
    encoder_kernel<<<2048, 512, 0, stream>>>(words, seg_ids, W1T, W2T, W3T,
                                             b1, b2, b3, enc);
    pred_kernel<<<128, 256, 0, stream>>>(enc, P1, pb1, P2, pb2, P3, pb3, out);
}